// Round 7
// baseline (357.578 us; speedup 1.0000x reference)
//
#include <hip/hip_runtime.h>
#include <limits.h>
#include <math.h>

// CalcImpute: per-row top-16-smallest (stable lex (value,index)) over 50000
// donors, then masked mean of gathered donor values.
// Round 7: scan+compact (round-6 structure) + software-pipelined K1.
// K1 streams the 1.64 GB dist matrix with a chip-wide LINEAR front
// (memcpy-shaped grid-stride, 2048 resident blocks x 16 KB chunks) and
// depth-1 prefetch so each wave keeps 8 x 1 KB loads in flight; rare
// candidates (val < TAU) are appended to per-row buckets as packed u64.
// K2 (4 rows/block) does exact top-16 per row from the bucket; rows with
// too-few/too-many candidates take an exact full-row rescan fallback.
// K0 zeroes counters (replay-safe).

#define NROWS 8192
#define NDON  50000
#define NF4   12500
#define K     16
#define TAU   1.0e-3f        // E[hits/row]=50; P(<16)~1e-9, P(>128)~1e-20
#define CAP   128
#define SUPER 100000         // super-chunks of 1024 f4 (16 KB) = whole matrix
#define GRID  2048

typedef unsigned long long u64;

__device__ __forceinline__ bool lexless(float v1, int i1, float v2, int i2) {
    return (v1 < v2) || ((v1 == v2) && (i1 < i2));
}
__device__ __forceinline__ float nanfix(float v) { return (v != v) ? 1e10f : v; }

// ---------------- K0: zero per-row counters ----------------
__global__ void k_zero(int* __restrict__ cnt) {
    const int i = blockIdx.x * blockDim.x + threadIdx.x;
    if (i < NROWS) cnt[i] = 0;
}

// ---------------- K1: linear-front scan + compact, prefetch depth 1 ----------------
__global__ void __launch_bounds__(256, 8)
k_scan(const float4* __restrict__ d4, u64* __restrict__ buck,
       int* __restrict__ cnt) {
    const int t = threadIdx.x;

#define EMIT(vf, ee)                                                        \
    if ((vf) < TAU) {                                                       \
        const int e_ = (ee);                                                \
        const int row_ = e_ / NDON;                                         \
        const int col_ = e_ - row_ * NDON;                                  \
        const int pos_ = atomicAdd(&cnt[row_], 1);                          \
        if (pos_ < CAP)                                                     \
            buck[(size_t)row_ * CAP + pos_] =                               \
                ((u64)__float_as_uint(vf) << 32) | (unsigned)col_;          \
    }
#define EMIT4(q, fi)                                                        \
    {                                                                       \
        const int e0_ = (fi) * 4;                                           \
        EMIT(q.x, e0_); EMIT(q.y, e0_ + 1);                                 \
        EMIT(q.z, e0_ + 2); EMIT(q.w, e0_ + 3);                             \
    }

    int sc = blockIdx.x;
    int F  = sc * 1024 + t;
    float4 a = d4[F], b = d4[F + 256], c = d4[F + 512], d = d4[F + 768];

#pragma unroll 1
    while (sc < SUPER) {
        const int nsc = sc + GRID;
        const bool more = (nsc < SUPER);
        // Prefetch next chunk (re-read current when done: legal + harmless).
        const int NFi = (more ? nsc : sc) * 1024 + t;
        const float4 na = d4[NFi], nb = d4[NFi + 256],
                     nc = d4[NFi + 512], nd = d4[NFi + 768];

        const float ma = fminf(fminf(a.x, a.y), fminf(a.z, a.w));
        const float mb = fminf(fminf(b.x, b.y), fminf(b.z, b.w));
        const float mc = fminf(fminf(c.x, c.y), fminf(c.z, c.w));
        const float md = fminf(fminf(d.x, d.y), fminf(d.z, d.w));
        if (fminf(fminf(ma, mb), fminf(mc, md)) < TAU) {   // rare
            if (ma < TAU) EMIT4(a, F);
            if (mb < TAU) EMIT4(b, F + 256);
            if (mc < TAU) EMIT4(c, F + 512);
            if (md < TAU) EMIT4(d, F + 768);
        }
        a = na; b = nb; c = nc; d = nd;
        sc = nsc; F = NFi;
    }
#undef EMIT4
#undef EMIT
}

// ---------------- K2: per-row merge (+exact fallback), 4 rows/block ----------------
__global__ void __launch_bounds__(256)
k_merge(const u64* __restrict__ buck, const int* __restrict__ cnt,
        const float* __restrict__ dist, const float* __restrict__ fitX,
        const int* __restrict__ mask, float* __restrict__ out, int nrows) {
    const int row  = blockIdx.x * 4 + (threadIdx.x >> 6);  // one wave per row
    const int lane = threadIdx.x & 63;
    if (row >= nrows) return;

    const int n = cnt[row];
    float s_w = 0.0f, s_wx = 0.0f;

    if (n >= K && n <= CAP) {
        // Bucket holds ALL row elements < TAU (none dropped) and >=16 exist,
        // so the global top-16 is inside. Packed key (valbits<<32)|col: u64
        // order == lex (val,col) for non-negative finite values.
        const u64* bp = buck + (size_t)row * CAP;
        u64 k0 = (lane < n)      ? bp[lane]      : ~0ull;
        u64 k1 = (lane + 64 < n) ? bp[lane + 64] : ~0ull;
        if (k1 < k0) { const u64 tt = k0; k0 = k1; k1 = tt; }
#pragma unroll
        for (int r = 0; r < K; ++r) {
            u64 mv = k0;                       // lane-local min (k0 <= k1)
#pragma unroll
            for (int m = 32; m >= 1; m >>= 1) {
                const u64 ov = __shfl_xor(mv, m, 64);
                if (ov < mv) mv = ov;
            }
            if (k0 == mv) { k0 = k1; k1 = ~0ull; }   // unique key pops
            const int col = (int)(unsigned)(mv & 0xffffffffu);
            const float w = 1.0f - (float)mask[col]; // uniform -> broadcast
            s_w  += w;
            s_wx += w * fitX[col];
        }
    } else {
        // Exact fallback: full-row rescan with replicated top-16 list.
        // (Essentially never taken on this data; correctness guarantee.)
        const float4* r4 = reinterpret_cast<const float4*>(dist + (size_t)row * NDON);
        float vals[K]; int idxs[K];
#pragma unroll
        for (int j = 0; j < K; ++j) { vals[j] = INFINITY; idxs[j] = INT_MAX; }
        float Tv = INFINITY;

#define PROC(ve, ie)                                                   \
    {                                                                  \
        unsigned long long bb_ = __ballot((ve) <= Tv);                 \
        while (bb_) {                                                  \
            const int src_ = __builtin_ctzll(bb_); bb_ &= bb_ - 1;     \
            const float cv_ = __shfl((ve), src_, 64);                  \
            const int   ci_ = __shfl((ie), src_, 64);                  \
            if (lexless(cv_, ci_, vals[K - 1], idxs[K - 1])) {         \
                vals[K - 1] = cv_; idxs[K - 1] = ci_;                  \
                for (int j_ = K - 1; j_ > 0; --j_) {                   \
                    if (lexless(vals[j_], idxs[j_],                    \
                                vals[j_ - 1], idxs[j_ - 1])) {         \
                        const float tv_ = vals[j_];                    \
                        const int ti_ = idxs[j_];                      \
                        vals[j_] = vals[j_ - 1]; idxs[j_] = idxs[j_ - 1]; \
                        vals[j_ - 1] = tv_; idxs[j_ - 1] = ti_;        \
                    } else break;                                      \
                }                                                      \
            }                                                          \
        }                                                              \
    }

        for (int it = 0; it < 196; ++it) {
            const int f4i = it * 64 + lane;
            float4 q;
            if (f4i < NF4) {
                q = r4[f4i];
            } else {
                q.x = q.y = q.z = q.w = INFINITY;
            }
            const float x0 = nanfix(q.x), x1 = nanfix(q.y),
                        x2 = nanfix(q.z), x3 = nanfix(q.w);
            const int e0 = f4i * 4;
            PROC(x0, e0 + 0); PROC(x1, e0 + 1);
            PROC(x2, e0 + 2); PROC(x3, e0 + 3);
            Tv = vals[K - 1];
        }
#undef PROC
#pragma unroll
        for (int r = 0; r < K; ++r) {
            const int col = idxs[r];
            const float w = 1.0f - (float)mask[col];
            s_w  += w;
            s_wx += w * fitX[col];
        }
    }

    if (lane == 0) {
        out[row] = s_wx / ((s_w == 0.0f) ? 1.0f : s_w);
    }
}

// ---------------- monolithic fallback (round-3 kernel, 387 us) ----------------
// Used only if ws_size is too small for the bucket scheme.
__device__ __forceinline__ void insert16m(float (&vals)[K], int (&idxs)[K],
                                          float cv, int ci) {
    if (!lexless(cv, ci, vals[K - 1], idxs[K - 1])) return;
    bool prev = true;
#pragma unroll
    for (int j = K - 1; j >= 1; --j) {
        const bool up = lexless(cv, ci, vals[j - 1], idxs[j - 1]);
        const float nv = up ? vals[j - 1] : (prev ? cv : vals[j]);
        const int   ni = up ? idxs[j - 1] : (prev ? ci : idxs[j]);
        vals[j] = nv; idxs[j] = ni;
        prev = up;
    }
    if (prev) { vals[0] = cv; idxs[0] = ci; }
}

#define CE(va, ia, vb, ib)                                         \
    {                                                              \
        const bool sw_ = lexless(vb, ib, va, ia);                  \
        const float tv_ = va; const int ti_ = ia;                  \
        va = sw_ ? vb : va; ia = sw_ ? ib : ia;                    \
        vb = sw_ ? tv_ : vb; ib = sw_ ? ti_ : ib;                  \
    }

__global__ void __launch_bounds__(256, 4)
calc_impute_mono(const float* __restrict__ dist,
                 const float* __restrict__ fitX,
                 const int*   __restrict__ mask,
                 float* __restrict__ out,
                 int nrows)
{
    const int gtid = blockIdx.x * blockDim.x + threadIdx.x;
    const int wrow = gtid >> 6;
    const int lane = threadIdx.x & 63;
    if (wrow >= nrows) return;

    const float4* __restrict__ r4 =
        reinterpret_cast<const float4*>(dist + (size_t)wrow * NDON);

    float4 d = r4[lane];
    float l0 = nanfix(d.x), l1 = nanfix(d.y), l2 = nanfix(d.z), l3 = nanfix(d.w);
    int   j0 = lane * 4, j1 = j0 + 1, j2 = j0 + 2, j3 = j0 + 3;
    CE(l0, j0, l1, j1); CE(l2, j2, l3, j3);
    CE(l0, j0, l2, j2); CE(l1, j1, l3, j3);
    CE(l1, j1, l2, j2);

    float vals[K]; int idxs[K];
#pragma unroll
    for (int r = 0; r < K; ++r) {
        float mv = l0; int mi = j0;
#pragma unroll
        for (int m = 32; m >= 1; m >>= 1) {
            const float ov = __shfl_xor(mv, m, 64);
            const int   oi = __shfl_xor(mi, m, 64);
            if (lexless(ov, oi, mv, mi)) { mv = ov; mi = oi; }
        }
        vals[r] = mv; idxs[r] = mi;
        if (l0 == mv && j0 == mi) {
            l0 = l1; j0 = j1; l1 = l2; j1 = j2; l2 = l3; j2 = j3;
            l3 = INFINITY; j3 = INT_MAX;
        }
    }
    float Tv = vals[K - 1];

#define PROCM(ve, ie)                                                  \
    {                                                                  \
        unsigned long long bb_ = __ballot((ve) <= Tv);                 \
        while (bb_) {                                                  \
            const int src_ = __builtin_ctzll(bb_); bb_ &= bb_ - 1;     \
            const float cv_ = __shfl((ve), src_, 64);                  \
            const int   ci_ = __shfl((ie), src_, 64);                  \
            insert16m(vals, idxs, cv_, ci_);                           \
        }                                                              \
    }

    const float4* p0 = r4 + 64 + lane;
    float4 c0 = p0[0], c1 = p0[64], c2 = p0[128], c3 = p0[192];
#pragma unroll 1
    for (int s = 0; s < 48; ++s) {
        float4 n0, n1, n2, n3;
        const bool more = (s + 1 < 48);
        if (more) {
            const float4* pn = r4 + 64 + (s + 1) * 256 + lane;
            n0 = pn[0]; n1 = pn[64]; n2 = pn[128]; n3 = pn[192];
        }
        const float m0 = fminf(fminf(c0.x, c0.y), fminf(c0.z, c0.w));
        const float m1 = fminf(fminf(c1.x, c1.y), fminf(c1.z, c1.w));
        const float m2 = fminf(fminf(c2.x, c2.y), fminf(c2.z, c2.w));
        const float m3 = fminf(fminf(c3.x, c3.y), fminf(c3.z, c3.w));
        if (__any(fminf(fminf(m0, m1), fminf(m2, m3)) <= Tv)) {
            const int e0 = (64 + s * 256 + lane) * 4;
            PROCM(c0.x, e0 + 0);   PROCM(c0.y, e0 + 1);
            PROCM(c0.z, e0 + 2);   PROCM(c0.w, e0 + 3);
            PROCM(c1.x, e0 + 256); PROCM(c1.y, e0 + 257);
            PROCM(c1.z, e0 + 258); PROCM(c1.w, e0 + 259);
            PROCM(c2.x, e0 + 512); PROCM(c2.y, e0 + 513);
            PROCM(c2.z, e0 + 514); PROCM(c2.w, e0 + 515);
            PROCM(c3.x, e0 + 768); PROCM(c3.y, e0 + 769);
            PROCM(c3.z, e0 + 770); PROCM(c3.w, e0 + 771);
            Tv = vals[K - 1];
        }
        c0 = n0; c1 = n1; c2 = n2; c3 = n3;
    }
#pragma unroll 1
    for (int t = 0; t < 3; ++t) {
        const int f4i = 12352 + t * 64 + lane;
        float4 e;
        if (f4i < NF4) { e = r4[f4i]; }
        else { e.x = e.y = e.z = e.w = INFINITY; }
        const int b0 = f4i * 4;
        PROCM(e.x, b0 + 0); PROCM(e.y, b0 + 1);
        PROCM(e.z, b0 + 2); PROCM(e.w, b0 + 3);
    }
#undef PROCM

    float s_w = 0.0f, s_wx = 0.0f;
#pragma unroll
    for (int r = 0; r < K; ++r) {
        const int mi = idxs[r];
        const float w = 1.0f - (float)mask[mi];
        s_w  += w;
        s_wx += w * fitX[mi];
    }
    if (lane == 0) {
        out[wrow] = s_wx / ((s_w == 0.0f) ? 1.0f : s_w);
    }
}

extern "C" void kernel_launch(void* const* d_in, const int* in_sizes, int n_in,
                              void* d_out, int out_size, void* d_ws, size_t ws_size,
                              hipStream_t stream) {
    const float* dist = (const float*)d_in[0];
    // d_in[1] is n_neighbors (==16, fixed; K hardcoded)
    const float* fitX = (const float*)d_in[2];
    const int*   mask = (const int*)d_in[3];
    float* out = (float*)d_out;
    const int nrows = out_size;                  // 8192

    const size_t needed = (size_t)NROWS * sizeof(int)
                        + (size_t)NROWS * CAP * sizeof(u64);
    if (ws_size >= needed) {
        int* cnt  = (int*)d_ws;
        u64* buck = (u64*)((char*)d_ws + NROWS * sizeof(int));
        k_zero<<<(NROWS + 255) / 256, 256, 0, stream>>>(cnt);
        k_scan<<<GRID, 256, 0, stream>>>(
            reinterpret_cast<const float4*>(dist), buck, cnt);
        k_merge<<<(nrows + 3) / 4, 256, 0, stream>>>(
            buck, cnt, dist, fitX, mask, out, nrows);
    } else {
        const int threads = 256;
        const int blocks = (nrows * 64 + threads - 1) / threads;
        calc_impute_mono<<<blocks, threads, 0, stream>>>(dist, fitX, mask, out, nrows);
    }
}

// Round 8
// 311.583 us; speedup vs baseline: 1.1476x; 1.1476x over previous
//
#include <hip/hip_runtime.h>
#include <limits.h>
#include <math.h>

// CalcImpute: per-row top-16-smallest (stable lex (value,index)) over 50000
// donors, then masked mean of gathered donor values.
// Round 8: scan+compact with (1) NONTEMPORAL loads (read-once stream should
// not allocate in L2) and (2) 64 KB per-block chunks walked as 4 sequential
// 16 KB sub-steps (4x per-block DRAM contiguity, 4x fewer concurrent
// fronts). No prefetch (round-7 A/B: null). K2 (4 rows/block) exact top-16
// from buckets; exact full-row rescan fallback for out-of-band rows; K0
// zeroes counters (replay-safe).

#define NROWS  8192
#define NDON   50000
#define NF4    12500
#define K      16
#define TAU    1.0e-3f       // E[hits/row]=50; P(<16)~1e-9, P(>128)~1e-20
#define CAP    128
#define CHUNKS 25000         // 64 KB chunks (4096 f4) = whole matrix
#define GRID   2048

typedef unsigned long long u64;
typedef float f4v __attribute__((ext_vector_type(4)));

__device__ __forceinline__ bool lexless(float v1, int i1, float v2, int i2) {
    return (v1 < v2) || ((v1 == v2) && (i1 < i2));
}
__device__ __forceinline__ float nanfix(float v) { return (v != v) ? 1e10f : v; }

// ---------------- K0: zero per-row counters ----------------
__global__ void k_zero(int* __restrict__ cnt) {
    const int i = blockIdx.x * blockDim.x + threadIdx.x;
    if (i < NROWS) cnt[i] = 0;
}

// ---------------- K1: linear-front scan + compact ----------------
__global__ void __launch_bounds__(256, 8)
k_scan(const float* __restrict__ dist, u64* __restrict__ buck,
       int* __restrict__ cnt) {
    const f4v* __restrict__ d4 = reinterpret_cast<const f4v*>(dist);
    const int t = threadIdx.x;

#define EMIT(vf, ee)                                                        \
    if ((vf) < TAU) {                                                       \
        const int e_ = (ee);                                                \
        const int row_ = e_ / NDON;                                         \
        const int col_ = e_ - row_ * NDON;                                  \
        const int pos_ = atomicAdd(&cnt[row_], 1);                          \
        if (pos_ < CAP)                                                     \
            buck[(size_t)row_ * CAP + pos_] =                               \
                ((u64)__float_as_uint(vf) << 32) | (unsigned)col_;          \
    }
#define EMIT4(q, fi)                                                        \
    {                                                                       \
        const int e0_ = (fi) * 4;                                           \
        EMIT(q[0], e0_); EMIT(q[1], e0_ + 1);                               \
        EMIT(q[2], e0_ + 2); EMIT(q[3], e0_ + 3);                           \
    }

#pragma unroll 1
    for (int sc = blockIdx.x; sc < CHUNKS; sc += GRID) {
        const int cbase = sc * 4096 + t;      // block walks 64 KB contiguous
#pragma unroll 1
        for (int sub = 0; sub < 4; ++sub) {
            const int F = cbase + sub * 1024;
            const f4v a = __builtin_nontemporal_load(d4 + F);
            const f4v b = __builtin_nontemporal_load(d4 + F + 256);
            const f4v c = __builtin_nontemporal_load(d4 + F + 512);
            const f4v d = __builtin_nontemporal_load(d4 + F + 768);
            const float ma = fminf(fminf(a[0], a[1]), fminf(a[2], a[3]));
            const float mb = fminf(fminf(b[0], b[1]), fminf(b[2], b[3]));
            const float mc = fminf(fminf(c[0], c[1]), fminf(c[2], c[3]));
            const float md = fminf(fminf(d[0], d[1]), fminf(d[2], d[3]));
            if (fminf(fminf(ma, mb), fminf(mc, md)) < TAU) {   // rare
                if (ma < TAU) EMIT4(a, F);
                if (mb < TAU) EMIT4(b, F + 256);
                if (mc < TAU) EMIT4(c, F + 512);
                if (md < TAU) EMIT4(d, F + 768);
            }
        }
    }
#undef EMIT4
#undef EMIT
}

// ---------------- K2: per-row merge (+exact fallback), 4 rows/block ----------------
__global__ void __launch_bounds__(256)
k_merge(const u64* __restrict__ buck, const int* __restrict__ cnt,
        const float* __restrict__ dist, const float* __restrict__ fitX,
        const int* __restrict__ mask, float* __restrict__ out, int nrows) {
    const int row  = blockIdx.x * 4 + (threadIdx.x >> 6);  // one wave per row
    const int lane = threadIdx.x & 63;
    if (row >= nrows) return;

    const int n = cnt[row];
    float s_w = 0.0f, s_wx = 0.0f;

    if (n >= K && n <= CAP) {
        // Bucket holds ALL row elements < TAU (none dropped) and >=16 exist,
        // so the global top-16 is inside. Packed key (valbits<<32)|col: u64
        // order == lex (val,col) for non-negative finite values.
        const u64* bp = buck + (size_t)row * CAP;
        u64 k0 = (lane < n)      ? bp[lane]      : ~0ull;
        u64 k1 = (lane + 64 < n) ? bp[lane + 64] : ~0ull;
        if (k1 < k0) { const u64 tt = k0; k0 = k1; k1 = tt; }
#pragma unroll
        for (int r = 0; r < K; ++r) {
            u64 mv = k0;                       // lane-local min (k0 <= k1)
#pragma unroll
            for (int m = 32; m >= 1; m >>= 1) {
                const u64 ov = __shfl_xor(mv, m, 64);
                if (ov < mv) mv = ov;
            }
            if (k0 == mv) { k0 = k1; k1 = ~0ull; }   // unique key pops
            const int col = (int)(unsigned)(mv & 0xffffffffu);
            const float w = 1.0f - (float)mask[col]; // uniform -> broadcast
            s_w  += w;
            s_wx += w * fitX[col];
        }
    } else {
        // Exact fallback: full-row rescan with replicated top-16 list.
        // (Essentially never taken on this data; correctness guarantee.)
        const float4* r4 = reinterpret_cast<const float4*>(dist + (size_t)row * NDON);
        float vals[K]; int idxs[K];
#pragma unroll
        for (int j = 0; j < K; ++j) { vals[j] = INFINITY; idxs[j] = INT_MAX; }
        float Tv = INFINITY;

#define PROC(ve, ie)                                                   \
    {                                                                  \
        unsigned long long bb_ = __ballot((ve) <= Tv);                 \
        while (bb_) {                                                  \
            const int src_ = __builtin_ctzll(bb_); bb_ &= bb_ - 1;     \
            const float cv_ = __shfl((ve), src_, 64);                  \
            const int   ci_ = __shfl((ie), src_, 64);                  \
            if (lexless(cv_, ci_, vals[K - 1], idxs[K - 1])) {         \
                vals[K - 1] = cv_; idxs[K - 1] = ci_;                  \
                for (int j_ = K - 1; j_ > 0; --j_) {                   \
                    if (lexless(vals[j_], idxs[j_],                    \
                                vals[j_ - 1], idxs[j_ - 1])) {         \
                        const float tv_ = vals[j_];                    \
                        const int ti_ = idxs[j_];                      \
                        vals[j_] = vals[j_ - 1]; idxs[j_] = idxs[j_ - 1]; \
                        vals[j_ - 1] = tv_; idxs[j_ - 1] = ti_;        \
                    } else break;                                      \
                }                                                      \
            }                                                          \
        }                                                              \
    }

        for (int it = 0; it < 196; ++it) {
            const int f4i = it * 64 + lane;
            float4 q;
            if (f4i < NF4) {
                q = r4[f4i];
            } else {
                q.x = q.y = q.z = q.w = INFINITY;
            }
            const float x0 = nanfix(q.x), x1 = nanfix(q.y),
                        x2 = nanfix(q.z), x3 = nanfix(q.w);
            const int e0 = f4i * 4;
            PROC(x0, e0 + 0); PROC(x1, e0 + 1);
            PROC(x2, e0 + 2); PROC(x3, e0 + 3);
            Tv = vals[K - 1];
        }
#undef PROC
#pragma unroll
        for (int r = 0; r < K; ++r) {
            const int col = idxs[r];
            const float w = 1.0f - (float)mask[col];
            s_w  += w;
            s_wx += w * fitX[col];
        }
    }

    if (lane == 0) {
        out[row] = s_wx / ((s_w == 0.0f) ? 1.0f : s_w);
    }
}

// ---------------- monolithic fallback (round-3 kernel, 387 us) ----------------
// Used only if ws_size is too small for the bucket scheme.
__device__ __forceinline__ void insert16m(float (&vals)[K], int (&idxs)[K],
                                          float cv, int ci) {
    if (!lexless(cv, ci, vals[K - 1], idxs[K - 1])) return;
    bool prev = true;
#pragma unroll
    for (int j = K - 1; j >= 1; --j) {
        const bool up = lexless(cv, ci, vals[j - 1], idxs[j - 1]);
        const float nv = up ? vals[j - 1] : (prev ? cv : vals[j]);
        const int   ni = up ? idxs[j - 1] : (prev ? ci : idxs[j]);
        vals[j] = nv; idxs[j] = ni;
        prev = up;
    }
    if (prev) { vals[0] = cv; idxs[0] = ci; }
}

#define CE(va, ia, vb, ib)                                         \
    {                                                              \
        const bool sw_ = lexless(vb, ib, va, ia);                  \
        const float tv_ = va; const int ti_ = ia;                  \
        va = sw_ ? vb : va; ia = sw_ ? ib : ia;                    \
        vb = sw_ ? tv_ : vb; ib = sw_ ? ti_ : ib;                  \
    }

__global__ void __launch_bounds__(256, 4)
calc_impute_mono(const float* __restrict__ dist,
                 const float* __restrict__ fitX,
                 const int*   __restrict__ mask,
                 float* __restrict__ out,
                 int nrows)
{
    const int gtid = blockIdx.x * blockDim.x + threadIdx.x;
    const int wrow = gtid >> 6;
    const int lane = threadIdx.x & 63;
    if (wrow >= nrows) return;

    const float4* __restrict__ r4 =
        reinterpret_cast<const float4*>(dist + (size_t)wrow * NDON);

    float4 d = r4[lane];
    float l0 = nanfix(d.x), l1 = nanfix(d.y), l2 = nanfix(d.z), l3 = nanfix(d.w);
    int   j0 = lane * 4, j1 = j0 + 1, j2 = j0 + 2, j3 = j0 + 3;
    CE(l0, j0, l1, j1); CE(l2, j2, l3, j3);
    CE(l0, j0, l2, j2); CE(l1, j1, l3, j3);
    CE(l1, j1, l2, j2);

    float vals[K]; int idxs[K];
#pragma unroll
    for (int r = 0; r < K; ++r) {
        float mv = l0; int mi = j0;
#pragma unroll
        for (int m = 32; m >= 1; m >>= 1) {
            const float ov = __shfl_xor(mv, m, 64);
            const int   oi = __shfl_xor(mi, m, 64);
            if (lexless(ov, oi, mv, mi)) { mv = ov; mi = oi; }
        }
        vals[r] = mv; idxs[r] = mi;
        if (l0 == mv && j0 == mi) {
            l0 = l1; j0 = j1; l1 = l2; j1 = j2; l2 = l3; j2 = j3;
            l3 = INFINITY; j3 = INT_MAX;
        }
    }
    float Tv = vals[K - 1];

#define PROCM(ve, ie)                                                  \
    {                                                                  \
        unsigned long long bb_ = __ballot((ve) <= Tv);                 \
        while (bb_) {                                                  \
            const int src_ = __builtin_ctzll(bb_); bb_ &= bb_ - 1;     \
            const float cv_ = __shfl((ve), src_, 64);                  \
            const int   ci_ = __shfl((ie), src_, 64);                  \
            insert16m(vals, idxs, cv_, ci_);                           \
        }                                                              \
    }

    const float4* p0 = r4 + 64 + lane;
    float4 c0 = p0[0], c1 = p0[64], c2 = p0[128], c3 = p0[192];
#pragma unroll 1
    for (int s = 0; s < 48; ++s) {
        float4 n0, n1, n2, n3;
        const bool more = (s + 1 < 48);
        if (more) {
            const float4* pn = r4 + 64 + (s + 1) * 256 + lane;
            n0 = pn[0]; n1 = pn[64]; n2 = pn[128]; n3 = pn[192];
        }
        const float m0 = fminf(fminf(c0.x, c0.y), fminf(c0.z, c0.w));
        const float m1 = fminf(fminf(c1.x, c1.y), fminf(c1.z, c1.w));
        const float m2 = fminf(fminf(c2.x, c2.y), fminf(c2.z, c2.w));
        const float m3 = fminf(fminf(c3.x, c3.y), fminf(c3.z, c3.w));
        if (__any(fminf(fminf(m0, m1), fminf(m2, m3)) <= Tv)) {
            const int e0 = (64 + s * 256 + lane) * 4;
            PROCM(c0.x, e0 + 0);   PROCM(c0.y, e0 + 1);
            PROCM(c0.z, e0 + 2);   PROCM(c0.w, e0 + 3);
            PROCM(c1.x, e0 + 256); PROCM(c1.y, e0 + 257);
            PROCM(c1.z, e0 + 258); PROCM(c1.w, e0 + 259);
            PROCM(c2.x, e0 + 512); PROCM(c2.y, e0 + 513);
            PROCM(c2.z, e0 + 514); PROCM(c2.w, e0 + 515);
            PROCM(c3.x, e0 + 768); PROCM(c3.y, e0 + 769);
            PROCM(c3.z, e0 + 770); PROCM(c3.w, e0 + 771);
            Tv = vals[K - 1];
        }
        c0 = n0; c1 = n1; c2 = n2; c3 = n3;
    }
#pragma unroll 1
    for (int t = 0; t < 3; ++t) {
        const int f4i = 12352 + t * 64 + lane;
        float4 e;
        if (f4i < NF4) { e = r4[f4i]; }
        else { e.x = e.y = e.z = e.w = INFINITY; }
        const int b0 = f4i * 4;
        PROCM(e.x, b0 + 0); PROCM(e.y, b0 + 1);
        PROCM(e.z, b0 + 2); PROCM(e.w, b0 + 3);
    }
#undef PROCM

    float s_w = 0.0f, s_wx = 0.0f;
#pragma unroll
    for (int r = 0; r < K; ++r) {
        const int mi = idxs[r];
        const float w = 1.0f - (float)mask[mi];
        s_w  += w;
        s_wx += w * fitX[mi];
    }
    if (lane == 0) {
        out[wrow] = s_wx / ((s_w == 0.0f) ? 1.0f : s_w);
    }
}

extern "C" void kernel_launch(void* const* d_in, const int* in_sizes, int n_in,
                              void* d_out, int out_size, void* d_ws, size_t ws_size,
                              hipStream_t stream) {
    const float* dist = (const float*)d_in[0];
    // d_in[1] is n_neighbors (==16, fixed; K hardcoded)
    const float* fitX = (const float*)d_in[2];
    const int*   mask = (const int*)d_in[3];
    float* out = (float*)d_out;
    const int nrows = out_size;                  // 8192

    const size_t needed = (size_t)NROWS * sizeof(int)
                        + (size_t)NROWS * CAP * sizeof(u64);
    if (ws_size >= needed) {
        int* cnt  = (int*)d_ws;
        u64* buck = (u64*)((char*)d_ws + NROWS * sizeof(int));
        k_zero<<<(NROWS + 255) / 256, 256, 0, stream>>>(cnt);
        k_scan<<<GRID, 256, 0, stream>>>(dist, buck, cnt);
        k_merge<<<(nrows + 3) / 4, 256, 0, stream>>>(
            buck, cnt, dist, fitX, mask, out, nrows);
    } else {
        const int threads = 256;
        const int blocks = (nrows * 64 + threads - 1) / threads;
        calc_impute_mono<<<blocks, threads, 0, stream>>>(dist, fitX, mask, out, nrows);
    }
}

// Round 9
// 311.126 us; speedup vs baseline: 1.1493x; 1.0015x over previous
//
#include <hip/hip_runtime.h>
#include <limits.h>
#include <math.h>

// CalcImpute: per-row top-16-smallest (stable lex (value,index)) over 50000
// donors, then masked mean of gathered donor values.
// Round 9: round-8 structure (linear-front scan+compact, nontemporal loads,
// 64 KB block-chunks) with two overhead fixes:
//   (a) tail-balanced K1: 12 uniform 64 KB rounds + one 16 KB round where
//       1696/2048 blocks take one sub-chunk each (no 20%-machine tail round)
//   (b) counter zeroing via hipMemsetAsync instead of a kernel dispatch.
// K2 (4 rows/block) exact top-16 from buckets; exact full-row rescan
// fallback for out-of-band rows.

#define NROWS    8192
#define NDON     50000
#define NF4      12500
#define K        16
#define TAU      1.0e-3f     // E[hits/row]=50; P(<16)~1e-9, P(>128)~1e-20
#define CAP      128
#define GRID     2048
#define FULLR    12          // 12 rounds x 2048 blocks x 64 KB chunks
#define TAILSUB  1696        // remaining 1,736,704 f4 = 1696 x 1024-f4 subchunks
#define TAILBASE 100663296   // 24576 * 4096 (f4 index where tail starts)

typedef unsigned long long u64;
typedef float f4v __attribute__((ext_vector_type(4)));

__device__ __forceinline__ bool lexless(float v1, int i1, float v2, int i2) {
    return (v1 < v2) || ((v1 == v2) && (i1 < i2));
}
__device__ __forceinline__ float nanfix(float v) { return (v != v) ? 1e10f : v; }

// ---------------- K1: linear-front scan + compact ----------------
__global__ void __launch_bounds__(256, 8)
k_scan(const float* __restrict__ dist, u64* __restrict__ buck,
       int* __restrict__ cnt) {
    const f4v* __restrict__ d4 = reinterpret_cast<const f4v*>(dist);
    const int t = threadIdx.x;

#define EMIT(vf, ee)                                                        \
    if ((vf) < TAU) {                                                       \
        const int e_ = (ee);                                                \
        const int row_ = e_ / NDON;                                         \
        const int col_ = e_ - row_ * NDON;                                  \
        const int pos_ = atomicAdd(&cnt[row_], 1);                          \
        if (pos_ < CAP)                                                     \
            buck[(size_t)row_ * CAP + pos_] =                               \
                ((u64)__float_as_uint(vf) << 32) | (unsigned)col_;          \
    }
#define SUBSTEP(F)                                                          \
    {                                                                       \
        const f4v a = __builtin_nontemporal_load(d4 + (F));                 \
        const f4v b = __builtin_nontemporal_load(d4 + (F) + 256);           \
        const f4v c = __builtin_nontemporal_load(d4 + (F) + 512);           \
        const f4v d = __builtin_nontemporal_load(d4 + (F) + 768);           \
        const float ma = fminf(fminf(a[0], a[1]), fminf(a[2], a[3]));       \
        const float mb = fminf(fminf(b[0], b[1]), fminf(b[2], b[3]));       \
        const float mc = fminf(fminf(c[0], c[1]), fminf(c[2], c[3]));       \
        const float md = fminf(fminf(d[0], d[1]), fminf(d[2], d[3]));       \
        if (fminf(fminf(ma, mb), fminf(mc, md)) < TAU) {  /* rare */        \
            const int e0_ = (F) * 4;                                        \
            if (ma < TAU) { EMIT(a[0], e0_);        EMIT(a[1], e0_ + 1);    \
                            EMIT(a[2], e0_ + 2);    EMIT(a[3], e0_ + 3); }  \
            if (mb < TAU) { EMIT(b[0], e0_ + 1024); EMIT(b[1], e0_ + 1025); \
                            EMIT(b[2], e0_ + 1026); EMIT(b[3], e0_ + 1027); }\
            if (mc < TAU) { EMIT(c[0], e0_ + 2048); EMIT(c[1], e0_ + 2049); \
                            EMIT(c[2], e0_ + 2050); EMIT(c[3], e0_ + 2051); }\
            if (md < TAU) { EMIT(d[0], e0_ + 3072); EMIT(d[1], e0_ + 3073); \
                            EMIT(d[2], e0_ + 3074); EMIT(d[3], e0_ + 3075); }\
        }                                                                   \
    }

    // 12 uniform rounds: block walks a contiguous 64 KB chunk per round.
#pragma unroll 1
    for (int r = 0; r < FULLR; ++r) {
        const int cbase = (r * GRID + blockIdx.x) * 4096 + t;
#pragma unroll 1
        for (int sub = 0; sub < 4; ++sub) {
            SUBSTEP(cbase + sub * 1024);
        }
    }
    // Balanced tail: one 16 KB sub-chunk for blocks 0..1695.
    if (blockIdx.x < TAILSUB) {
        SUBSTEP(TAILBASE + blockIdx.x * 1024 + t);
    }
#undef SUBSTEP
#undef EMIT
}

// ---------------- K2: per-row merge (+exact fallback), 4 rows/block ----------------
__global__ void __launch_bounds__(256)
k_merge(const u64* __restrict__ buck, const int* __restrict__ cnt,
        const float* __restrict__ dist, const float* __restrict__ fitX,
        const int* __restrict__ mask, float* __restrict__ out, int nrows) {
    const int row  = blockIdx.x * 4 + (threadIdx.x >> 6);  // one wave per row
    const int lane = threadIdx.x & 63;
    if (row >= nrows) return;

    const int n = cnt[row];
    float s_w = 0.0f, s_wx = 0.0f;

    if (n >= K && n <= CAP) {
        // Bucket holds ALL row elements < TAU (none dropped) and >=16 exist,
        // so the global top-16 is inside. Packed key (valbits<<32)|col: u64
        // order == lex (val,col) for non-negative finite values.
        const u64* bp = buck + (size_t)row * CAP;
        u64 k0 = (lane < n)      ? bp[lane]      : ~0ull;
        u64 k1 = (lane + 64 < n) ? bp[lane + 64] : ~0ull;
        if (k1 < k0) { const u64 tt = k0; k0 = k1; k1 = tt; }
#pragma unroll
        for (int r = 0; r < K; ++r) {
            u64 mv = k0;                       // lane-local min (k0 <= k1)
#pragma unroll
            for (int m = 32; m >= 1; m >>= 1) {
                const u64 ov = __shfl_xor(mv, m, 64);
                if (ov < mv) mv = ov;
            }
            if (k0 == mv) { k0 = k1; k1 = ~0ull; }   // unique key pops
            const int col = (int)(unsigned)(mv & 0xffffffffu);
            const float w = 1.0f - (float)mask[col]; // uniform -> broadcast
            s_w  += w;
            s_wx += w * fitX[col];
        }
    } else {
        // Exact fallback: full-row rescan with replicated top-16 list.
        // (Essentially never taken on this data; correctness guarantee.)
        const float4* r4 = reinterpret_cast<const float4*>(dist + (size_t)row * NDON);
        float vals[K]; int idxs[K];
#pragma unroll
        for (int j = 0; j < K; ++j) { vals[j] = INFINITY; idxs[j] = INT_MAX; }
        float Tv = INFINITY;

#define PROC(ve, ie)                                                   \
    {                                                                  \
        unsigned long long bb_ = __ballot((ve) <= Tv);                 \
        while (bb_) {                                                  \
            const int src_ = __builtin_ctzll(bb_); bb_ &= bb_ - 1;     \
            const float cv_ = __shfl((ve), src_, 64);                  \
            const int   ci_ = __shfl((ie), src_, 64);                  \
            if (lexless(cv_, ci_, vals[K - 1], idxs[K - 1])) {         \
                vals[K - 1] = cv_; idxs[K - 1] = ci_;                  \
                for (int j_ = K - 1; j_ > 0; --j_) {                   \
                    if (lexless(vals[j_], idxs[j_],                    \
                                vals[j_ - 1], idxs[j_ - 1])) {         \
                        const float tv_ = vals[j_];                    \
                        const int ti_ = idxs[j_];                      \
                        vals[j_] = vals[j_ - 1]; idxs[j_] = idxs[j_ - 1]; \
                        vals[j_ - 1] = tv_; idxs[j_ - 1] = ti_;        \
                    } else break;                                      \
                }                                                      \
            }                                                          \
        }                                                              \
    }

        for (int it = 0; it < 196; ++it) {
            const int f4i = it * 64 + lane;
            float4 q;
            if (f4i < NF4) {
                q = r4[f4i];
            } else {
                q.x = q.y = q.z = q.w = INFINITY;
            }
            const float x0 = nanfix(q.x), x1 = nanfix(q.y),
                        x2 = nanfix(q.z), x3 = nanfix(q.w);
            const int e0 = f4i * 4;
            PROC(x0, e0 + 0); PROC(x1, e0 + 1);
            PROC(x2, e0 + 2); PROC(x3, e0 + 3);
            Tv = vals[K - 1];
        }
#undef PROC
#pragma unroll
        for (int r = 0; r < K; ++r) {
            const int col = idxs[r];
            const float w = 1.0f - (float)mask[col];
            s_w  += w;
            s_wx += w * fitX[col];
        }
    }

    if (lane == 0) {
        out[row] = s_wx / ((s_w == 0.0f) ? 1.0f : s_w);
    }
}

// ---------------- monolithic fallback (round-3 kernel, 387 us) ----------------
// Used only if ws_size is too small for the bucket scheme.
__device__ __forceinline__ void insert16m(float (&vals)[K], int (&idxs)[K],
                                          float cv, int ci) {
    if (!lexless(cv, ci, vals[K - 1], idxs[K - 1])) return;
    bool prev = true;
#pragma unroll
    for (int j = K - 1; j >= 1; --j) {
        const bool up = lexless(cv, ci, vals[j - 1], idxs[j - 1]);
        const float nv = up ? vals[j - 1] : (prev ? cv : vals[j]);
        const int   ni = up ? idxs[j - 1] : (prev ? ci : idxs[j]);
        vals[j] = nv; idxs[j] = ni;
        prev = up;
    }
    if (prev) { vals[0] = cv; idxs[0] = ci; }
}

#define CE(va, ia, vb, ib)                                         \
    {                                                              \
        const bool sw_ = lexless(vb, ib, va, ia);                  \
        const float tv_ = va; const int ti_ = ia;                  \
        va = sw_ ? vb : va; ia = sw_ ? ib : ia;                    \
        vb = sw_ ? tv_ : vb; ib = sw_ ? ti_ : ib;                  \
    }

__global__ void __launch_bounds__(256, 4)
calc_impute_mono(const float* __restrict__ dist,
                 const float* __restrict__ fitX,
                 const int*   __restrict__ mask,
                 float* __restrict__ out,
                 int nrows)
{
    const int gtid = blockIdx.x * blockDim.x + threadIdx.x;
    const int wrow = gtid >> 6;
    const int lane = threadIdx.x & 63;
    if (wrow >= nrows) return;

    const float4* __restrict__ r4 =
        reinterpret_cast<const float4*>(dist + (size_t)wrow * NDON);

    float4 d = r4[lane];
    float l0 = nanfix(d.x), l1 = nanfix(d.y), l2 = nanfix(d.z), l3 = nanfix(d.w);
    int   j0 = lane * 4, j1 = j0 + 1, j2 = j0 + 2, j3 = j0 + 3;
    CE(l0, j0, l1, j1); CE(l2, j2, l3, j3);
    CE(l0, j0, l2, j2); CE(l1, j1, l3, j3);
    CE(l1, j1, l2, j2);

    float vals[K]; int idxs[K];
#pragma unroll
    for (int r = 0; r < K; ++r) {
        float mv = l0; int mi = j0;
#pragma unroll
        for (int m = 32; m >= 1; m >>= 1) {
            const float ov = __shfl_xor(mv, m, 64);
            const int   oi = __shfl_xor(mi, m, 64);
            if (lexless(ov, oi, mv, mi)) { mv = ov; mi = oi; }
        }
        vals[r] = mv; idxs[r] = mi;
        if (l0 == mv && j0 == mi) {
            l0 = l1; j0 = j1; l1 = l2; j1 = j2; l2 = l3; j2 = j3;
            l3 = INFINITY; j3 = INT_MAX;
        }
    }
    float Tv = vals[K - 1];

#define PROCM(ve, ie)                                                  \
    {                                                                  \
        unsigned long long bb_ = __ballot((ve) <= Tv);                 \
        while (bb_) {                                                  \
            const int src_ = __builtin_ctzll(bb_); bb_ &= bb_ - 1;     \
            const float cv_ = __shfl((ve), src_, 64);                  \
            const int   ci_ = __shfl((ie), src_, 64);                  \
            insert16m(vals, idxs, cv_, ci_);                           \
        }                                                              \
    }

    const float4* p0 = r4 + 64 + lane;
    float4 c0 = p0[0], c1 = p0[64], c2 = p0[128], c3 = p0[192];
#pragma unroll 1
    for (int s = 0; s < 48; ++s) {
        float4 n0, n1, n2, n3;
        const bool more = (s + 1 < 48);
        if (more) {
            const float4* pn = r4 + 64 + (s + 1) * 256 + lane;
            n0 = pn[0]; n1 = pn[64]; n2 = pn[128]; n3 = pn[192];
        }
        const float m0 = fminf(fminf(c0.x, c0.y), fminf(c0.z, c0.w));
        const float m1 = fminf(fminf(c1.x, c1.y), fminf(c1.z, c1.w));
        const float m2 = fminf(fminf(c2.x, c2.y), fminf(c2.z, c2.w));
        const float m3 = fminf(fminf(c3.x, c3.y), fminf(c3.z, c3.w));
        if (__any(fminf(fminf(m0, m1), fminf(m2, m3)) <= Tv)) {
            const int e0 = (64 + s * 256 + lane) * 4;
            PROCM(c0.x, e0 + 0);   PROCM(c0.y, e0 + 1);
            PROCM(c0.z, e0 + 2);   PROCM(c0.w, e0 + 3);
            PROCM(c1.x, e0 + 256); PROCM(c1.y, e0 + 257);
            PROCM(c1.z, e0 + 258); PROCM(c1.w, e0 + 259);
            PROCM(c2.x, e0 + 512); PROCM(c2.y, e0 + 513);
            PROCM(c2.z, e0 + 514); PROCM(c2.w, e0 + 515);
            PROCM(c3.x, e0 + 768); PROCM(c3.y, e0 + 769);
            PROCM(c3.z, e0 + 770); PROCM(c3.w, e0 + 771);
            Tv = vals[K - 1];
        }
        c0 = n0; c1 = n1; c2 = n2; c3 = n3;
    }
#pragma unroll 1
    for (int t = 0; t < 3; ++t) {
        const int f4i = 12352 + t * 64 + lane;
        float4 e;
        if (f4i < NF4) { e = r4[f4i]; }
        else { e.x = e.y = e.z = e.w = INFINITY; }
        const int b0 = f4i * 4;
        PROCM(e.x, b0 + 0); PROCM(e.y, b0 + 1);
        PROCM(e.z, b0 + 2); PROCM(e.w, b0 + 3);
    }
#undef PROCM

    float s_w = 0.0f, s_wx = 0.0f;
#pragma unroll
    for (int r = 0; r < K; ++r) {
        const int mi = idxs[r];
        const float w = 1.0f - (float)mask[mi];
        s_w  += w;
        s_wx += w * fitX[mi];
    }
    if (lane == 0) {
        out[wrow] = s_wx / ((s_w == 0.0f) ? 1.0f : s_w);
    }
}

extern "C" void kernel_launch(void* const* d_in, const int* in_sizes, int n_in,
                              void* d_out, int out_size, void* d_ws, size_t ws_size,
                              hipStream_t stream) {
    const float* dist = (const float*)d_in[0];
    // d_in[1] is n_neighbors (==16, fixed; K hardcoded)
    const float* fitX = (const float*)d_in[2];
    const int*   mask = (const int*)d_in[3];
    float* out = (float*)d_out;
    const int nrows = out_size;                  // 8192

    const size_t needed = (size_t)NROWS * sizeof(int)
                        + (size_t)NROWS * CAP * sizeof(u64);
    if (ws_size >= needed) {
        int* cnt  = (int*)d_ws;
        u64* buck = (u64*)((char*)d_ws + NROWS * sizeof(int));
        hipMemsetAsync(cnt, 0, NROWS * sizeof(int), stream);
        k_scan<<<GRID, 256, 0, stream>>>(dist, buck, cnt);
        k_merge<<<(nrows + 3) / 4, 256, 0, stream>>>(
            buck, cnt, dist, fitX, mask, out, nrows);
    } else {
        const int threads = 256;
        const int blocks = (nrows * 64 + threads - 1) / threads;
        calc_impute_mono<<<blocks, threads, 0, stream>>>(dist, fitX, mask, out, nrows);
    }
}